// Round 11
// baseline (207.900 us; speedup 1.0000x reference)
//
#include <hip/hip_runtime.h>

#define N_   512
#define V_   3889
#define V3   11667      // V_*3
#define J_   35
#define NB_  20
#define PF_K 306        // 34*9
#define KP2  352        // K = [pf 306 | beta 20 | pad 26], 11 k-steps of 32
#define KS2  11
#define EP2  11776      // padded e dim (23 chunks x 512)
#define JCP  112        // padded (j,c) rows: 105 -> 112
#define KB_  23         // K-split chunks in jrgemm
#define ECH  512        // e per chunk (KB_*ECH == EP2)
#define XROWS 544       // jrgemm output rows: 512 bodies + 32 vtsd rows
#define PLN  60928      // XROWS*112, one partial plane

typedef __attribute__((ext_vector_type(8))) short short8;
typedef __attribute__((ext_vector_type(4))) float f32x4;

__constant__ int c_parents[J_] = {0,0,1,2,3,4,5,6,7,8,9,6,11,12,13,6,15,16,17,18,
                                  16,20,21,22,23,16,25,26,27,28,29,30,16,1,1};

static __device__ __forceinline__ unsigned short f2bf(float x) {
  union { float f; unsigned int u; } v; v.f = x;
  unsigned int r = v.u + 0x7FFF + ((v.u >> 16) & 1);   // round-to-nearest-even
  return (unsigned short)(r >> 16);
}

// ===== prep A (pure layout, fine-grained): ==================================
#define PA_WTS 245
#define PA_PD  2024                     // 184 e-chunks x 11 oct4-groups
#define PA_JB  644                      // 112*1472 octets / 256
#define PA_VS  365                      // ceil(32*V3/1024)
#define PA_BLOCKS (PA_WTS + PA_PD + PA_JB + PA_VS)
__global__ __launch_bounds__(256) void k_prep_a(
    const float* __restrict__ Jr,  const float* __restrict__ wts,
    const float* __restrict__ pd,  const float* __restrict__ sd,
    const float* __restrict__ vt,
    unsigned short* __restrict__ wtsB, unsigned short* __restrict__ pdT,
    unsigned short* __restrict__ JrBigT, float* __restrict__ vtsd) {
  int b = blockIdx.x;
  int t = threadIdx.x;
  if (b < PA_WTS) {                      // ---- wtsB bf16 ----
    int v   = b * 16 + (t >> 4);
    int jk0 = (t & 15) * 4;
    unsigned short pk[4];
#pragma unroll
    for (int i = 0; i < 4; ++i) {
      int j = jk0 + i;
      float x = (v < V_ && j < J_) ? wts[(size_t)v * J_ + j] : 0.f;
      pk[i] = f2bf(x);
    }
    *(unsigned long long*)(wtsB + (size_t)v * 64 + jk0) = *(unsigned long long*)pk;
  } else if (b < PA_WTS + PA_PD) {       // ---- pdT2 bf16, fragment order ----
    int pp = b - PA_WTS;
    int ec = pp % 184, o4 = pp / 184;
    int e  = ec * 64 + (t & 63);
    int oc = o4 * 4 + (t >> 6);          // 0..43
    int k0 = oc * 8;
    bool ev = e < V3;
    union { unsigned short u[8]; short8 s; } pk;
#pragma unroll
    for (int ii = 0; ii < 8; ++ii) {
      int k = k0 + ii;
      float x = 0.f;
      if (ev && k < PF_K)            x = pd[(size_t)k * V3 + e];
      else if (ev && k < PF_K + NB_) x = sd[(size_t)(k - PF_K) * V3 + e];
      pk.u[ii] = f2bf(x);
    }
    size_t dst = (size_t)(e >> 4) * 704 + (size_t)(oc >> 2) * 64
               + (oc & 3) * 16 + (e & 15);
    *(short8*)(pdT + dst * 8) = pk.s;
  } else if (b < PA_WTS + PA_PD + PA_JB) {  // ---- JrBig2 bf16, fragment order ----
    int o = (b - (PA_WTS + PA_PD)) * 256 + t;   // octet id, < 112*1472
    int jc = o / 1472;
    int oc = o - jc * 1472;              // e-octet within row
    int eo = oc * 8;
    int jj = jc / 3, cc = jc - jj * 3;
    union { unsigned short u[8]; short8 s; } pk;
#pragma unroll
    for (int i = 0; i < 8; ++i) {
      int e = eo + i;
      int v = e / 3, ce = e - v * 3;
      float x = (jc < 105 && e < V3 && ce == cc) ? Jr[v * J_ + jj] : 0.f;
      pk.u[i] = f2bf(x);
    }
    size_t dst = (size_t)(oc >> 2) * 448 + (size_t)(jc >> 4) * 64
               + (oc & 3) * 16 + (jc & 15);
    *(short8*)(JrBigT + dst * 8) = pk.s;
  } else {                               // ---- vtsd copy ----
    int f0 = (b - (PA_WTS + PA_PD + PA_JB)) * 1024 + t * 4;
#pragma unroll
    for (int k = 0; k < 4; ++k) {
      int f = f0 + k;
      if (f < 32 * V3) {
        int row = f / V3, col = f - row * V3;
        float x = 0.f;
        if (row == 0) x = vt[col];
        else if (row <= NB_) x = sd[(size_t)(row - 1) * V3 + col];
        vtsd[f] = x;
      }
    }
  }
}

// ===== jrgemm: planes[kb][row][jc] = sum_{e in chunk} JrBig[jc][e]*X[row][e]
// LDS-staged X (coalesced global reads), XCD-swizzled 1-D grid:
// g = kb + 24*nt -> all nt's of one kb share an XCD (A-slice L2-resident).
#define XSTR 516
__global__ __launch_bounds__(64) void k_jrgemm(
    const float* __restrict__ X, const float* __restrict__ X2,
    const unsigned short* __restrict__ JrBigT, float* __restrict__ planes) {
  __shared__ float xs[16][XSTR];
  int g = blockIdx.x;
  int kb = g % 24;
  if (kb >= KB_) return;
  int nt = g / 24;
  int lane = threadIdx.x;
  int q = lane >> 4, c = lane & 15;
  int e0 = kb * ECH;
  const short8* Ap = (const short8*)JrBigT;

  // ---- stage 16 rows x 512 e into LDS (coalesced; zero-fill OOB) ----
  if (e0 + ECH <= V3) {
#pragma unroll
    for (int i = 0; i < 32; ++i) {
      int row = i >> 1;
      int cvf = ((i & 1) * 64 + lane) * 4;
      int row_g = nt * 16 + row;
      const float* src = (row_g < N_) ? X + (size_t)row_g * V3
                                      : X2 + (size_t)(row_g - N_) * V3;
      *(f32x4*)&xs[row][cvf] = *(const f32x4*)(src + e0 + cvf);
    }
  } else {
#pragma unroll
    for (int i = 0; i < 32; ++i) {
      int row = i >> 1;
      int cvf = ((i & 1) * 64 + lane) * 4;
      int row_g = nt * 16 + row;
      const float* src = (row_g < N_) ? X + (size_t)row_g * V3
                                      : X2 + (size_t)(row_g - N_) * V3;
      f32x4 val = (f32x4){0.f, 0.f, 0.f, 0.f};
#pragma unroll
      for (int k2 = 0; k2 < 4; ++k2) {
        int e = e0 + cvf + k2;
        if (e < V3) val[k2] = src[e];
      }
      *(f32x4*)&xs[row][cvf] = val;
    }
  }
  // single-wave block: in-wave LDS ordering, no barrier needed

  f32x4 acc[7];
#pragma unroll
  for (int tt = 0; tt < 7; ++tt) acc[tt] = (f32x4){0.f, 0.f, 0.f, 0.f};

#pragma unroll
  for (int ks = 0; ks < ECH / 32; ++ks) {
    int ecol = ks * 32 + q * 8;
    f32x4 x0 = *(const f32x4*)&xs[c][ecol];
    f32x4 x1 = *(const f32x4*)&xs[c][ecol + 4];
    union { unsigned short u[8]; short8 s; } bq;
#pragma unroll
    for (int i = 0; i < 4; ++i) { bq.u[i] = f2bf(x0[i]); bq.u[4 + i] = f2bf(x1[i]); }
#pragma unroll
    for (int tt = 0; tt < 7; ++tt) {
      short8 a = Ap[(size_t)(kb * 16 + ks) * 448 + tt * 64 + lane];
      acc[tt] = __builtin_amdgcn_mfma_f32_16x16x32_bf16(a, bq.s, acc[tt], 0, 0, 0);
    }
  }

  int row = nt * 16 + c;
  float* pl = planes + (size_t)kb * PLN + (size_t)row * JCP;
#pragma unroll
  for (int tt = 0; tt < 7; ++tt)
    *(f32x4*)(pl + tt * 16 + q * 4) = acc[tt];
}

// ===== fold: rows<512 -> dst[n*105+jc]; rows>=512 -> dst2[(n-512)*105+jc] ===
__global__ __launch_bounds__(256) void k_fold(
    const float* __restrict__ planes, float* __restrict__ dst,
    float* __restrict__ dst2, int total) {
  int g = blockIdx.x * 256 + threadIdx.x;
  if (g >= total) return;
  int n = g / 105, jc = g - n * 105;
  float s = 0.f;
#pragma unroll
  for (int kb = 0; kb < KB_; ++kb)
    s += planes[(size_t)kb * PLN + n * JCP + jc];
  if (n < N_) dst[n * 105 + jc] = s;
  else dst2[(n - N_) * 105 + jc] = s;
}

// ===== Rodrigues + Jp finalize + chain -> Rs, pfA, AwB ======================
// One wave per body, wave-private LDS, no barriers.
__global__ __launch_bounds__(64) void k_chain_rod(
    const float* __restrict__ theta, const float* __restrict__ JpRaw,
    const float* __restrict__ vtsdJr,
    const float* __restrict__ se,    const float* __restrict__ trans,
    const float* __restrict__ beta,
    float* __restrict__ Rs_out, unsigned short* __restrict__ pfA,
    unsigned short* __restrict__ AwB) {
  __shared__ float loc[J_][12];
  __shared__ float res[J_][12];
  __shared__ float Jp_s[J_][3];
  int l = threadIdx.x;
  int n = blockIdx.x;
  int mt = n >> 4, m = n & 15;

  float r[9];
  if (l < J_) {
    int j = l;
    const float* th = theta + n * (J_ * 3) + j * 3;
    float t0 = th[0], t1 = th[1], t2 = th[2];
    float angle = sqrtf(t0 * t0 + t1 * t1 + t2 * t2 + 1e-8f);
    float inv = 1.0f / angle;
    float r0 = t0 * inv, r1 = t1 * inv, r2 = t2 * inv;
    float s, c;
    sincosf(angle, &s, &c);
    float omc = 1.0f - c;
    r[0] = c + omc * r0 * r0;      r[1] = omc * r0 * r1 - s * r2;  r[2] = omc * r0 * r2 + s * r1;
    r[3] = omc * r1 * r0 + s * r2; r[4] = c + omc * r1 * r1;       r[5] = omc * r1 * r2 - s * r0;
    r[6] = omc * r2 * r0 - s * r1; r[7] = omc * r2 * r1 + s * r0;  r[8] = c + omc * r2 * r2;

    float* ro = Rs_out + (size_t)n * (J_ * 9) + j * 9;
#pragma unroll
    for (int k = 0; k < 9; ++k) ro[k] = r[k];
    if (j > 0) {
#pragma unroll
      for (int kk = 0; kk < 9; ++kk) {
        int k = (j - 1) * 9 + kk;
        float v = r[kk] - ((kk == 0 || kk == 4 || kk == 8) ? 1.0f : 0.0f);
        size_t idx = ((((size_t)mt * KS2 + (k >> 5)) * 4 + ((k >> 3) & 3)) * 16 + m) * 8 + (k & 7);
        pfA[idx] = f2bf(v);
      }
    }
    // Jp finalize: Jp = JpRaw + vtJr + beta @ sdJr
    const float* bn = beta + n * NB_;
#pragma unroll
    for (int cc = 0; cc < 3; ++cc) {
      int jc = j * 3 + cc;
      float val = JpRaw[n * 105 + jc] + vtsdJr[jc];
#pragma unroll
      for (int bb = 0; bb < NB_; ++bb)
        val += bn[bb] * vtsdJr[(1 + bb) * 105 + jc];
      Jp_s[j][cc] = val;
    }
  } else {
    // lanes 35..63: AwB j-pad zero + pfA beta rows + pfA k-pad zeros
    unsigned short* An = AwB + (size_t)n * 16 * 64 + l;
#pragma unroll
    for (int d = 0; d < 16; ++d) An[d * 64] = 0;
    if (l < 55) {                    // beta -> k = 306 + (l-35)
      int k = PF_K + (l - 35);
      size_t idx = ((((size_t)mt * KS2 + (k >> 5)) * 4 + ((k >> 3) & 3)) * 16 + m) * 8 + (k & 7);
      pfA[idx] = f2bf(beta[n * NB_ + (l - 35)]);
    } else {                         // zeros k = 326..351
      for (int k = PF_K + NB_ + (l - 55); k < KP2; k += 9) {
        size_t idx = ((((size_t)mt * KS2 + (k >> 5)) * 4 + ((k >> 3) & 3)) * 16 + m) * 8 + (k & 7);
        pfA[idx] = 0;
      }
    }
  }
  // no barrier: single wave, LDS deps are in-order within a wave

  if (l < J_) {
    int j = l;
    if (j == 0) {
#pragma unroll
      for (int rr = 0; rr < 3; ++rr) {
        loc[0][rr * 4 + 0] = r[rr * 3 + 0];
        loc[0][rr * 4 + 1] = r[rr * 3 + 1];
        loc[0][rr * 4 + 2] = r[rr * 3 + 2];
        loc[0][rr * 4 + 3] = Jp_s[0][rr];
      }
#pragma unroll
      for (int k = 0; k < 12; ++k) res[0][k] = loc[0][k];
    } else {
      int p = c_parents[j];
      float si[3], sp[3], jh[3];
#pragma unroll
      for (int cidx = 0; cidx < 3; ++cidx) {
        si[cidx] = se[n * 105 + j * 3 + cidx];
        sp[cidx] = se[n * 105 + p * 3 + cidx];
        jh[cidx] = Jp_s[j][cidx] - Jp_s[p][cidx];
      }
#pragma unroll
      for (int rr = 0; rr < 3; ++rr) {
        float invp = 1.0f / sp[rr];
        loc[j][rr * 4 + 0] = r[rr * 3 + 0] * si[0] * invp;
        loc[j][rr * 4 + 1] = r[rr * 3 + 1] * si[1] * invp;
        loc[j][rr * 4 + 2] = r[rr * 3 + 2] * si[2] * invp;
        loc[j][rr * 4 + 3] = jh[rr];
      }
    }
  }

  for (int i = 1; i < J_; ++i) {
    if (l < 12) {
      int p = c_parents[i];
      int rr = l >> 2, cc = l & 3;
      float acc = (cc == 3) ? res[p][rr * 4 + 3] : 0.f;
#pragma unroll
      for (int k = 0; k < 3; ++k)
        acc += res[p][rr * 4 + k] * loc[i][k * 4 + cc];
      res[i][l] = acc;
    }
  }

  if (l < J_) {
    int j = l;
    float jx = Jp_s[j][0];
    float jy = Jp_s[j][1];
    float jz = Jp_s[j][2];
    unsigned short* An = AwB + (size_t)n * 16 * 64 + j;
#pragma unroll
    for (int rr = 0; rr < 3; ++rr) {
      float a0 = res[j][rr * 4 + 0];
      float a1 = res[j][rr * 4 + 1];
      float a2 = res[j][rr * 4 + 2];
      float a3 = res[j][rr * 4 + 3] - (a0 * jx + a1 * jy + a2 * jz)
               + trans[n * 3 + rr];
      An[(rr * 4 + 0) * 64] = f2bf(a0);
      An[(rr * 4 + 1) * 64] = f2bf(a1);
      An[(rr * 4 + 2) * 64] = f2bf(a2);
      An[(rr * 4 + 3) * 64] = f2bf(a3);
    }
  }
}

// ===== fused: v_posed (MFMA K=352) + LDS + skin (MFMA) -> verts =============
// 1-D grid 448: g = bx + 56*by -> all by's of one bx share an XCD
// (pdT bx-slice fetched once per XCD instead of 8x).
#define LSTR 244
__global__ __launch_bounds__(256) void k_vposed_skin(
    const unsigned short* __restrict__ pfA, const unsigned short* __restrict__ pdT,
    const unsigned short* __restrict__ AwB, const unsigned short* __restrict__ wtsB,
    const float* __restrict__ vt, const float* __restrict__ deform,
    float* __restrict__ verts) {
  __shared__ float lds[64 * LSTR];
  int g = blockIdx.x;
  int by = g / 56;
  int bx = g - by * 56;
  if (bx >= 49) return;
  int t = threadIdx.x;
  int wv = t >> 6, lane = t & 63;
  int q = lane >> 4, col = lane & 15;
  int mtg0 = by * 4;
  int ebase = bx * 240 + wv * 64;
  int e16b = ebase >> 4;

  const short8* Ap = (const short8*)pfA;
  const short8* Bp = (const short8*)pdT;

  // ---- phase 1: [pf|beta] @ [pd;sd]  (K=352, M=64) ----
  f32x4 acc[4][4];
#pragma unroll
  for (int mt = 0; mt < 4; ++mt)
#pragma unroll
    for (int et = 0; et < 4; ++et) acc[mt][et] = (f32x4){0.f, 0.f, 0.f, 0.f};

#pragma unroll
  for (int ks = 0; ks < KS2; ++ks) {
    short8 a[4];
#pragma unroll
    for (int mt = 0; mt < 4; ++mt)
      a[mt] = Ap[(((mtg0 + mt) * KS2 + ks) * 4 + q) * 16 + col];
    short8 b[4];
#pragma unroll
    for (int et = 0; et < 4; ++et)
      b[et] = Bp[(size_t)(e16b + et) * 704 + ks * 64 + lane];
#pragma unroll
    for (int mt = 0; mt < 4; ++mt)
#pragma unroll
      for (int et = 0; et < 4; ++et)
        acc[mt][et] = __builtin_amdgcn_mfma_f32_16x16x32_bf16(a[mt], b[et], acc[mt][et], 0, 0, 0);
  }

  // ---- phase 2a: stage raw acc into LDS ----
#pragma unroll
  for (int et = 0; et < 4; ++et) {
    int e_loc = wv * 64 + et * 16 + col;
    if (e_loc < 240) {
#pragma unroll
      for (int mt = 0; mt < 4; ++mt)
#pragma unroll
        for (int r = 0; r < 4; ++r)
          lds[(mt * 16 + q * 4 + r) * LSTR + e_loc] = acc[mt][et][r];
    }
  }
  __syncthreads();

  // ---- phase 2b: += vt + deform (vec4, wave-local rows; no barrier after) --
  if (lane < 60) {
    int e = bx * 240 + lane * 4;
    bool full = (e + 4 <= V3);
    f32x4 vt4 = (f32x4){0.f, 0.f, 0.f, 0.f};
    if (full) vt4 = *(const f32x4*)(vt + e);
    else {
#pragma unroll
      for (int k2 = 0; k2 < 4; ++k2) if (e + k2 < V3) vt4[k2] = vt[e + k2];
    }
#pragma unroll
    for (int i = 0; i < 16; ++i) {
      int n_loc = wv * 16 + i;
      int n = by * 64 + n_loc;
      const float* dp = deform + (size_t)n * V3 + e;
      f32x4 d4 = (f32x4){0.f, 0.f, 0.f, 0.f};
      if (full) d4 = *(const f32x4*)dp;
      else {
#pragma unroll
        for (int k2 = 0; k2 < 4; ++k2) if (e + k2 < V3) d4[k2] = dp[k2];
      }
      f32x4* lp = (f32x4*)&lds[n_loc * LSTR + lane * 4];
      *lp = *lp + vt4 + d4;
    }
  }

  // ---- phase 3: skin via MFMA, write final verts (rows wave-local) ----
  short8 bw0[5], bw1[5];
#pragma unroll
  for (int v5 = 0; v5 < 5; ++v5) {
    int v = bx * 80 + v5 * 16 + col;
    const short8* Wp = (const short8*)(wtsB + (size_t)v * 64);
    bw0[v5] = Wp[q];
    bw1[v5] = Wp[4 + q];
  }
#pragma unroll 2
  for (int ni = 0; ni < 16; ++ni) {
    int n_loc = wv * 16 + ni;
    int n = by * 64 + n_loc;
    const short8* Aq = (const short8*)(AwB + ((size_t)n * 16 + col) * 64);
    short8 a0 = Aq[q];
    short8 a1 = Aq[4 + q];
#pragma unroll
    for (int v5 = 0; v5 < 5; ++v5) {
      f32x4 s = (f32x4){0.f, 0.f, 0.f, 0.f};
      s = __builtin_amdgcn_mfma_f32_16x16x32_bf16(a0, bw0[v5], s, 0, 0, 0);
      s = __builtin_amdgcn_mfma_f32_16x16x32_bf16(a1, bw1[v5], s, 0, 0, 0);
      int vl = v5 * 16 + col;
      int v = bx * 80 + vl;
      if (v < V_ && q < 3) {
        float x = lds[n_loc * LSTR + 3 * vl + 0];
        float y = lds[n_loc * LSTR + 3 * vl + 1];
        float z = lds[n_loc * LSTR + 3 * vl + 2];
        verts[(size_t)n * V3 + 3 * v + q] = s[0] * x + s[1] * y + s[2] * z + s[3];
      }
    }
  }
}

extern "C" void kernel_launch(void* const* d_in, const int* in_sizes, int n_in,
                              void* d_out, int out_size, void* d_ws, size_t ws_size,
                              hipStream_t stream) {
  const float* beta   = (const float*)d_in[0];
  const float* theta  = (const float*)d_in[1];
  const float* se     = (const float*)d_in[2];
  const float* deform = (const float*)d_in[3];
  const float* trans  = (const float*)d_in[4];
  const float* vt     = (const float*)d_in[5];
  const float* sd     = (const float*)d_in[6];
  const float* pd     = (const float*)d_in[7];
  const float* Jr     = (const float*)d_in[8];
  const float* wts    = (const float*)d_in[9];

  float* out    = (float*)d_out;
  float* verts  = out;
  float* joints = out + (size_t)N_ * V3;
  float* Rs     = joints + (size_t)N_ * 105;

  char* w = (char*)d_ws;
  unsigned short* pdT    = (unsigned short*)w;                   //  8,290,304 B
  unsigned short* pfA    = (unsigned short*)(w + 8290304);       //    360,448 B
  float* planes = (float*)(w + 8650752);                         //  5,605,376 B (23 planes x 544 rows)
  float* JpRawF = (float*)(w + 14256128);                        //    215,040 B
  unsigned short* AwB    = (unsigned short*)(w + 14471168);      //  1,048,576 B
  unsigned short* wtsB   = (unsigned short*)(w + 15519744);      //    501,760 B
  unsigned short* JrBigT = (unsigned short*)(w + 16021504);      //  2,637,824 B
  float* vtsd   = (float*)(w + 18659328);                        //  1,493,376 B (32 x V3)
  float* vtsdJr = (float*)(w + 20152704);                        //      8,820 B

  k_prep_a<<<PA_BLOCKS, 256, 0, stream>>>(Jr, wts, pd, sd, vt,
                                          wtsB, pdT, JrBigT, vtsd);
  k_jrgemm<<<24 * 34, 64, 0, stream>>>(deform, vtsd, JrBigT, planes);
  k_fold<<<219, 256, 0, stream>>>(planes, JpRawF, vtsdJr, 533 * 105);
  k_chain_rod<<<N_, 64, 0, stream>>>(theta, JpRawF, vtsdJr, se, trans, beta,
                                     Rs, pfA, AwB);
  k_vposed_skin<<<448, 256, 0, stream>>>(pfA, pdT, AwB, wtsB, vt, deform, verts);
  k_jrgemm<<<24 * 32, 64, 0, stream>>>(verts, verts, JrBigT, planes);
  k_fold<<<210, 256, 0, stream>>>(planes, joints, vtsdJr, N_ * 105);
}

// Round 12
// 200.920 us; speedup vs baseline: 1.0347x; 1.0347x over previous
//
#include <hip/hip_runtime.h>

#define N_   512
#define V_   3889
#define V3   11667      // V_*3
#define J_   35
#define NB_  20
#define PF_K 306        // 34*9
#define KP2  352        // K = [pf 306 | beta 20 | pad 26], 11 k-steps of 32
#define KS2  11
#define EP2  11776      // padded e dim (23 chunks x 512)
#define JCP  112        // padded (j,c) rows: 105 -> 112
#define KB_  23         // K-split chunks in jrgemm
#define ECH  512        // e per chunk (KB_*ECH == EP2)
#define XROWS 544       // jrgemm output rows: 512 bodies + 32 vtsd rows
#define PLN  60928      // XROWS*112, one partial plane

typedef __attribute__((ext_vector_type(8))) short short8;
typedef __attribute__((ext_vector_type(4))) float f32x4;

__constant__ int c_parents[J_] = {0,0,1,2,3,4,5,6,7,8,9,6,11,12,13,6,15,16,17,18,
                                  16,20,21,22,23,16,25,26,27,28,29,30,16,1,1};

static __device__ __forceinline__ unsigned short f2bf(float x) {
  union { float f; unsigned int u; } v; v.f = x;
  unsigned int r = v.u + 0x7FFF + ((v.u >> 16) & 1);   // round-to-nearest-even
  return (unsigned short)(r >> 16);
}

// ===== prep A (pure layout, fine-grained): ==================================
#define PA_WTS 245
#define PA_PD  2024                     // 184 e-chunks x 11 oct4-groups
#define PA_JB  644                      // 112*1472 octets / 256
#define PA_VS  365                      // ceil(32*V3/1024)
#define PA_BLOCKS (PA_WTS + PA_PD + PA_JB + PA_VS)
__global__ __launch_bounds__(256) void k_prep_a(
    const float* __restrict__ Jr,  const float* __restrict__ wts,
    const float* __restrict__ pd,  const float* __restrict__ sd,
    const float* __restrict__ vt,
    unsigned short* __restrict__ wtsB, unsigned short* __restrict__ pdT,
    unsigned short* __restrict__ JrBigT, float* __restrict__ vtsd) {
  int b = blockIdx.x;
  int t = threadIdx.x;
  if (b < PA_WTS) {                      // ---- wtsB bf16 ----
    int v   = b * 16 + (t >> 4);
    int jk0 = (t & 15) * 4;
    unsigned short pk[4];
#pragma unroll
    for (int i = 0; i < 4; ++i) {
      int j = jk0 + i;
      float x = (v < V_ && j < J_) ? wts[(size_t)v * J_ + j] : 0.f;
      pk[i] = f2bf(x);
    }
    *(unsigned long long*)(wtsB + (size_t)v * 64 + jk0) = *(unsigned long long*)pk;
  } else if (b < PA_WTS + PA_PD) {       // ---- pdT2 bf16, fragment order ----
    int pp = b - PA_WTS;
    int ec = pp % 184, o4 = pp / 184;
    int e  = ec * 64 + (t & 63);
    int oc = o4 * 4 + (t >> 6);          // 0..43
    int k0 = oc * 8;
    bool ev = e < V3;
    union { unsigned short u[8]; short8 s; } pk;
#pragma unroll
    for (int ii = 0; ii < 8; ++ii) {
      int k = k0 + ii;
      float x = 0.f;
      if (ev && k < PF_K)            x = pd[(size_t)k * V3 + e];
      else if (ev && k < PF_K + NB_) x = sd[(size_t)(k - PF_K) * V3 + e];
      pk.u[ii] = f2bf(x);
    }
    size_t dst = (size_t)(e >> 4) * 704 + (size_t)(oc >> 2) * 64
               + (oc & 3) * 16 + (e & 15);
    *(short8*)(pdT + dst * 8) = pk.s;
  } else if (b < PA_WTS + PA_PD + PA_JB) {  // ---- JrBig2 bf16, fragment order ----
    int o = (b - (PA_WTS + PA_PD)) * 256 + t;   // octet id, < 112*1472
    int jc = o / 1472;
    int oc = o - jc * 1472;              // e-octet within row
    int eo = oc * 8;
    int jj = jc / 3, cc = jc - jj * 3;
    union { unsigned short u[8]; short8 s; } pk;
#pragma unroll
    for (int i = 0; i < 8; ++i) {
      int e = eo + i;
      int v = e / 3, ce = e - v * 3;
      float x = (jc < 105 && e < V3 && ce == cc) ? Jr[v * J_ + jj] : 0.f;
      pk.u[i] = f2bf(x);
    }
    size_t dst = (size_t)(oc >> 2) * 448 + (size_t)(jc >> 4) * 64
               + (oc & 3) * 16 + (jc & 15);
    *(short8*)(JrBigT + dst * 8) = pk.s;
  } else {                               // ---- vtsd copy ----
    int f0 = (b - (PA_WTS + PA_PD + PA_JB)) * 1024 + t * 4;
#pragma unroll
    for (int k = 0; k < 4; ++k) {
      int f = f0 + k;
      if (f < 32 * V3) {
        int row = f / V3, col = f - row * V3;
        float x = 0.f;
        if (row == 0) x = vt[col];
        else if (row <= NB_) x = sd[(size_t)(row - 1) * V3 + col];
        vtsd[f] = x;
      }
    }
  }
}

// ===== jrgemm: planes[kb][row][jc] = sum_{e in chunk} JrBig[jc][e]*X[row][e]
// rows 0..511 from X (bodies); rows 512..543 from X2 (vtsd). MFMA bf16.
// (R10 configuration: direct X loads, 2-D grid — best measured.)
__global__ __launch_bounds__(64) void k_jrgemm(
    const float* __restrict__ X, const float* __restrict__ X2,
    const unsigned short* __restrict__ JrBigT, float* __restrict__ planes) {
  int lane = threadIdx.x;
  int q = lane >> 4, c = lane & 15;
  int row = blockIdx.x * 16 + c;
  int kb = blockIdx.y;
  int e0 = kb * ECH;
  const float* xr = (row < N_) ? X + (size_t)row * V3
                               : X2 + (size_t)(row - N_) * V3;
  const short8* Ap = (const short8*)JrBigT;

  f32x4 acc[7];
#pragma unroll
  for (int tt = 0; tt < 7; ++tt) acc[tt] = (f32x4){0.f, 0.f, 0.f, 0.f};

  bool safe = (e0 + ECH <= V3);
  if (safe) {
#pragma unroll
    for (int ks = 0; ks < ECH / 32; ++ks) {
      int eb = e0 + ks * 32 + q * 8;
      f32x4 x0 = *(const f32x4*)(xr + eb);
      f32x4 x1 = *(const f32x4*)(xr + eb + 4);
      union { unsigned short u[8]; short8 s; } bq;
#pragma unroll
      for (int i = 0; i < 4; ++i) { bq.u[i] = f2bf(x0[i]); bq.u[4 + i] = f2bf(x1[i]); }
#pragma unroll
      for (int tt = 0; tt < 7; ++tt) {
        short8 a = Ap[(size_t)(kb * 16 + ks) * 448 + tt * 64 + lane];
        acc[tt] = __builtin_amdgcn_mfma_f32_16x16x32_bf16(a, bq.s, acc[tt], 0, 0, 0);
      }
    }
  } else {                               // last chunk: zero-guard e >= V3
#pragma unroll
    for (int ks = 0; ks < ECH / 32; ++ks) {
      int eb = e0 + ks * 32 + q * 8;
      union { unsigned short u[8]; short8 s; } bq;
#pragma unroll
      for (int i = 0; i < 8; ++i) {
        int e = eb + i;
        float x = (e < V3) ? xr[e] : 0.f;
        bq.u[i] = f2bf(x);
      }
#pragma unroll
      for (int tt = 0; tt < 7; ++tt) {
        short8 a = Ap[(size_t)(kb * 16 + ks) * 448 + tt * 64 + lane];
        acc[tt] = __builtin_amdgcn_mfma_f32_16x16x32_bf16(a, bq.s, acc[tt], 0, 0, 0);
      }
    }
  }

  float* pl = planes + (size_t)kb * PLN + (size_t)row * JCP;
#pragma unroll
  for (int tt = 0; tt < 7; ++tt)
    *(f32x4*)(pl + tt * 16 + q * 4) = acc[tt];
}

// ===== fold: rows [row0, row0+total/105) -> dst (n<512) / dst2 (n>=512) =====
__global__ __launch_bounds__(256) void k_fold(
    const float* __restrict__ planes, float* __restrict__ dst,
    float* __restrict__ dst2, int row0, int total) {
  int g = blockIdx.x * 256 + threadIdx.x;
  if (g >= total) return;
  int n = row0 + g / 105, jc = g % 105;
  float s = 0.f;
#pragma unroll
  for (int kb = 0; kb < KB_; ++kb)
    s += planes[(size_t)kb * PLN + n * JCP + jc];
  if (n < N_) dst[n * 105 + jc] = s;
  else dst2[(n - N_) * 105 + jc] = s;
}

// ===== Rodrigues + inline Jp plane-fold + chain -> Rs, pfA, AwB =============
// One wave per body, wave-private LDS, no barriers. Jp folded from planes
// directly (R6-proven pattern) — removes the big fold dispatch.
__global__ __launch_bounds__(64) void k_chain_rod(
    const float* __restrict__ theta, const float* __restrict__ planes,
    const float* __restrict__ vtsdJr,
    const float* __restrict__ se,    const float* __restrict__ trans,
    const float* __restrict__ beta,
    float* __restrict__ Rs_out, unsigned short* __restrict__ pfA,
    unsigned short* __restrict__ AwB) {
  __shared__ float loc[J_][12];
  __shared__ float res[J_][12];
  __shared__ float Jp_s[J_][3];
  int l = threadIdx.x;
  int n = blockIdx.x;
  int mt = n >> 4, m = n & 15;

  float r[9];
  if (l < J_) {
    int j = l;
    const float* th = theta + n * (J_ * 3) + j * 3;
    float t0 = th[0], t1 = th[1], t2 = th[2];
    float angle = sqrtf(t0 * t0 + t1 * t1 + t2 * t2 + 1e-8f);
    float inv = 1.0f / angle;
    float r0 = t0 * inv, r1 = t1 * inv, r2 = t2 * inv;
    float s, c;
    sincosf(angle, &s, &c);
    float omc = 1.0f - c;
    r[0] = c + omc * r0 * r0;      r[1] = omc * r0 * r1 - s * r2;  r[2] = omc * r0 * r2 + s * r1;
    r[3] = omc * r1 * r0 + s * r2; r[4] = c + omc * r1 * r1;       r[5] = omc * r1 * r2 - s * r0;
    r[6] = omc * r2 * r0 - s * r1; r[7] = omc * r2 * r1 + s * r0;  r[8] = c + omc * r2 * r2;

    float* ro = Rs_out + (size_t)n * (J_ * 9) + j * 9;
#pragma unroll
    for (int k = 0; k < 9; ++k) ro[k] = r[k];
    if (j > 0) {
#pragma unroll
      for (int kk = 0; kk < 9; ++kk) {
        int k = (j - 1) * 9 + kk;
        float v = r[kk] - ((kk == 0 || kk == 4 || kk == 8) ? 1.0f : 0.0f);
        size_t idx = ((((size_t)mt * KS2 + (k >> 5)) * 4 + ((k >> 3) & 3)) * 16 + m) * 8 + (k & 7);
        pfA[idx] = f2bf(v);
      }
    }
    // Jp finalize: Jp = sum_kb planes[kb][n] + vtJr + beta @ sdJr
    const float* bn = beta + n * NB_;
#pragma unroll
    for (int cc = 0; cc < 3; ++cc) {
      int jc = j * 3 + cc;
      float val = vtsdJr[jc];
#pragma unroll
      for (int kb = 0; kb < KB_; ++kb)
        val += planes[(size_t)kb * PLN + n * JCP + jc];
#pragma unroll
      for (int bb = 0; bb < NB_; ++bb)
        val += bn[bb] * vtsdJr[(1 + bb) * 105 + jc];
      Jp_s[j][cc] = val;
    }
  } else {
    // lanes 35..63: AwB j-pad zero + pfA beta rows + pfA k-pad zeros
    unsigned short* An = AwB + (size_t)n * 16 * 64 + l;
#pragma unroll
    for (int d = 0; d < 16; ++d) An[d * 64] = 0;
    if (l < 55) {                    // beta -> k = 306 + (l-35)
      int k = PF_K + (l - 35);
      size_t idx = ((((size_t)mt * KS2 + (k >> 5)) * 4 + ((k >> 3) & 3)) * 16 + m) * 8 + (k & 7);
      pfA[idx] = f2bf(beta[n * NB_ + (l - 35)]);
    } else {                         // zeros k = 326..351
      for (int k = PF_K + NB_ + (l - 55); k < KP2; k += 9) {
        size_t idx = ((((size_t)mt * KS2 + (k >> 5)) * 4 + ((k >> 3) & 3)) * 16 + m) * 8 + (k & 7);
        pfA[idx] = 0;
      }
    }
  }
  // no barrier: single wave, LDS deps are in-order within a wave

  if (l < J_) {
    int j = l;
    if (j == 0) {
#pragma unroll
      for (int rr = 0; rr < 3; ++rr) {
        loc[0][rr * 4 + 0] = r[rr * 3 + 0];
        loc[0][rr * 4 + 1] = r[rr * 3 + 1];
        loc[0][rr * 4 + 2] = r[rr * 3 + 2];
        loc[0][rr * 4 + 3] = Jp_s[0][rr];
      }
#pragma unroll
      for (int k = 0; k < 12; ++k) res[0][k] = loc[0][k];
    } else {
      int p = c_parents[j];
      float si[3], sp[3], jh[3];
#pragma unroll
      for (int cidx = 0; cidx < 3; ++cidx) {
        si[cidx] = se[n * 105 + j * 3 + cidx];
        sp[cidx] = se[n * 105 + p * 3 + cidx];
        jh[cidx] = Jp_s[j][cidx] - Jp_s[p][cidx];
      }
#pragma unroll
      for (int rr = 0; rr < 3; ++rr) {
        float invp = 1.0f / sp[rr];
        loc[j][rr * 4 + 0] = r[rr * 3 + 0] * si[0] * invp;
        loc[j][rr * 4 + 1] = r[rr * 3 + 1] * si[1] * invp;
        loc[j][rr * 4 + 2] = r[rr * 3 + 2] * si[2] * invp;
        loc[j][rr * 4 + 3] = jh[rr];
      }
    }
  }

  for (int i = 1; i < J_; ++i) {
    if (l < 12) {
      int p = c_parents[i];
      int rr = l >> 2, cc = l & 3;
      float acc = (cc == 3) ? res[p][rr * 4 + 3] : 0.f;
#pragma unroll
      for (int k = 0; k < 3; ++k)
        acc += res[p][rr * 4 + k] * loc[i][k * 4 + cc];
      res[i][l] = acc;
    }
  }

  if (l < J_) {
    int j = l;
    float jx = Jp_s[j][0];
    float jy = Jp_s[j][1];
    float jz = Jp_s[j][2];
    unsigned short* An = AwB + (size_t)n * 16 * 64 + j;
#pragma unroll
    for (int rr = 0; rr < 3; ++rr) {
      float a0 = res[j][rr * 4 + 0];
      float a1 = res[j][rr * 4 + 1];
      float a2 = res[j][rr * 4 + 2];
      float a3 = res[j][rr * 4 + 3] - (a0 * jx + a1 * jy + a2 * jz)
               + trans[n * 3 + rr];
      An[(rr * 4 + 0) * 64] = f2bf(a0);
      An[(rr * 4 + 1) * 64] = f2bf(a1);
      An[(rr * 4 + 2) * 64] = f2bf(a2);
      An[(rr * 4 + 3) * 64] = f2bf(a3);
    }
  }
}

// ===== fused: v_posed (MFMA K=352) + LDS + skin (MFMA) -> verts =============
// grid(49, 8): block = 64 n x 240 e. phase2 split: 2a stage acc, 2b vec4 adds.
// (R10 configuration — best measured.)
#define LSTR 244
__global__ __launch_bounds__(256) void k_vposed_skin(
    const unsigned short* __restrict__ pfA, const unsigned short* __restrict__ pdT,
    const unsigned short* __restrict__ AwB, const unsigned short* __restrict__ wtsB,
    const float* __restrict__ vt, const float* __restrict__ deform,
    float* __restrict__ verts) {
  __shared__ float lds[64 * LSTR];
  int t = threadIdx.x;
  int wv = t >> 6, lane = t & 63;
  int q = lane >> 4, col = lane & 15;
  int bx = blockIdx.x, by = blockIdx.y;
  int mtg0 = by * 4;
  int ebase = bx * 240 + wv * 64;
  int e16b = ebase >> 4;

  const short8* Ap = (const short8*)pfA;
  const short8* Bp = (const short8*)pdT;

  // ---- phase 1: [pf|beta] @ [pd;sd]  (K=352, M=64) ----
  f32x4 acc[4][4];
#pragma unroll
  for (int mt = 0; mt < 4; ++mt)
#pragma unroll
    for (int et = 0; et < 4; ++et) acc[mt][et] = (f32x4){0.f, 0.f, 0.f, 0.f};

#pragma unroll
  for (int ks = 0; ks < KS2; ++ks) {
    short8 a[4];
#pragma unroll
    for (int mt = 0; mt < 4; ++mt)
      a[mt] = Ap[(((mtg0 + mt) * KS2 + ks) * 4 + q) * 16 + col];
    short8 b[4];
#pragma unroll
    for (int et = 0; et < 4; ++et)
      b[et] = Bp[(size_t)(e16b + et) * 704 + ks * 64 + lane];
#pragma unroll
    for (int mt = 0; mt < 4; ++mt)
#pragma unroll
      for (int et = 0; et < 4; ++et)
        acc[mt][et] = __builtin_amdgcn_mfma_f32_16x16x32_bf16(a[mt], b[et], acc[mt][et], 0, 0, 0);
  }

  // ---- phase 2a: stage raw acc into LDS ----
#pragma unroll
  for (int et = 0; et < 4; ++et) {
    int e_loc = wv * 64 + et * 16 + col;
    if (e_loc < 240) {
#pragma unroll
      for (int mt = 0; mt < 4; ++mt)
#pragma unroll
        for (int r = 0; r < 4; ++r)
          lds[(mt * 16 + q * 4 + r) * LSTR + e_loc] = acc[mt][et][r];
    }
  }
  __syncthreads();

  // ---- phase 2b: += vt + deform (vec4, wave-local rows; no barrier after) --
  if (lane < 60) {
    int e = bx * 240 + lane * 4;
    bool full = (e + 4 <= V3);
    f32x4 vt4 = (f32x4){0.f, 0.f, 0.f, 0.f};
    if (full) vt4 = *(const f32x4*)(vt + e);
    else {
#pragma unroll
      for (int k2 = 0; k2 < 4; ++k2) if (e + k2 < V3) vt4[k2] = vt[e + k2];
    }
#pragma unroll
    for (int i = 0; i < 16; ++i) {
      int n_loc = wv * 16 + i;
      int n = by * 64 + n_loc;
      const float* dp = deform + (size_t)n * V3 + e;
      f32x4 d4 = (f32x4){0.f, 0.f, 0.f, 0.f};
      if (full) d4 = *(const f32x4*)dp;
      else {
#pragma unroll
        for (int k2 = 0; k2 < 4; ++k2) if (e + k2 < V3) d4[k2] = dp[k2];
      }
      f32x4* lp = (f32x4*)&lds[n_loc * LSTR + lane * 4];
      *lp = *lp + vt4 + d4;
    }
  }

  // ---- phase 3: skin via MFMA, write final verts (rows wave-local) ----
  short8 bw0[5], bw1[5];
#pragma unroll
  for (int v5 = 0; v5 < 5; ++v5) {
    int v = bx * 80 + v5 * 16 + col;
    const short8* Wp = (const short8*)(wtsB + (size_t)v * 64);
    bw0[v5] = Wp[q];
    bw1[v5] = Wp[4 + q];
  }
#pragma unroll 2
  for (int ni = 0; ni < 16; ++ni) {
    int n_loc = wv * 16 + ni;
    int n = by * 64 + n_loc;
    const short8* Aq = (const short8*)(AwB + ((size_t)n * 16 + col) * 64);
    short8 a0 = Aq[q];
    short8 a1 = Aq[4 + q];
#pragma unroll
    for (int v5 = 0; v5 < 5; ++v5) {
      f32x4 s = (f32x4){0.f, 0.f, 0.f, 0.f};
      s = __builtin_amdgcn_mfma_f32_16x16x32_bf16(a0, bw0[v5], s, 0, 0, 0);
      s = __builtin_amdgcn_mfma_f32_16x16x32_bf16(a1, bw1[v5], s, 0, 0, 0);
      int vl = v5 * 16 + col;
      int v = bx * 80 + vl;
      if (v < V_ && q < 3) {
        float x = lds[n_loc * LSTR + 3 * vl + 0];
        float y = lds[n_loc * LSTR + 3 * vl + 1];
        float z = lds[n_loc * LSTR + 3 * vl + 2];
        verts[(size_t)n * V3 + 3 * v + q] = s[0] * x + s[1] * y + s[2] * z + s[3];
      }
    }
  }
}

extern "C" void kernel_launch(void* const* d_in, const int* in_sizes, int n_in,
                              void* d_out, int out_size, void* d_ws, size_t ws_size,
                              hipStream_t stream) {
  const float* beta   = (const float*)d_in[0];
  const float* theta  = (const float*)d_in[1];
  const float* se     = (const float*)d_in[2];
  const float* deform = (const float*)d_in[3];
  const float* trans  = (const float*)d_in[4];
  const float* vt     = (const float*)d_in[5];
  const float* sd     = (const float*)d_in[6];
  const float* pd     = (const float*)d_in[7];
  const float* Jr     = (const float*)d_in[8];
  const float* wts    = (const float*)d_in[9];

  float* out    = (float*)d_out;
  float* verts  = out;
  float* joints = out + (size_t)N_ * V3;
  float* Rs     = joints + (size_t)N_ * 105;

  char* w = (char*)d_ws;
  unsigned short* pdT    = (unsigned short*)w;                   //  8,290,304 B
  unsigned short* pfA    = (unsigned short*)(w + 8290304);       //    360,448 B
  float* planes = (float*)(w + 8650752);                         //  5,605,376 B (23 planes x 544 rows)
  float* JpRawF = (float*)(w + 14256128);                        //    215,040 B (unused dst slot)
  unsigned short* AwB    = (unsigned short*)(w + 14471168);      //  1,048,576 B
  unsigned short* wtsB   = (unsigned short*)(w + 15519744);      //    501,760 B
  unsigned short* JrBigT = (unsigned short*)(w + 16021504);      //  2,637,824 B
  float* vtsd   = (float*)(w + 18659328);                        //  1,493,376 B (32 x V3)
  float* vtsdJr = (float*)(w + 20152704);                        //      8,820 B

  k_prep_a<<<PA_BLOCKS, 256, 0, stream>>>(Jr, wts, pd, sd, vt,
                                          wtsB, pdT, JrBigT, vtsd);
  k_jrgemm<<<dim3(34, KB_), 64, 0, stream>>>(deform, vtsd, JrBigT, planes);
  k_fold<<<9, 256, 0, stream>>>(planes, JpRawF, vtsdJr, N_, 21 * 105);
  k_chain_rod<<<N_, 64, 0, stream>>>(theta, planes, vtsdJr, se, trans, beta,
                                     Rs, pfA, AwB);
  k_vposed_skin<<<dim3(49, 8), 256, 0, stream>>>(pfA, pdT, AwB, wtsB, vt, deform, verts);
  k_jrgemm<<<dim3(32, KB_), 64, 0, stream>>>(verts, verts, JrBigT, planes);
  k_fold<<<210, 256, 0, stream>>>(planes, joints, vtsdJr, 0, N_ * 105);
}

// Round 13
// 195.042 us; speedup vs baseline: 1.0659x; 1.0301x over previous
//
#include <hip/hip_runtime.h>

#define N_   512
#define V_   3889
#define V3   11667      // V_*3
#define J_   35
#define NB_  20
#define PF_K 306        // 34*9
#define KP2  352        // K = [pf 306 | beta 20 | pad 26], 11 k-steps of 32
#define KS2  11
#define EP2  11776      // padded e dim (23 chunks x 512)
#define JCP  112        // padded (j,c) rows: 105 -> 112
#define KB_  23         // K-split chunks in jrgemm
#define ECH  512        // e per chunk (KB_*ECH == EP2)
#define XROWS 544       // jrgemm output rows: 512 bodies + 32 vtsd rows
#define PLN  60928      // XROWS*112, one partial plane

typedef __attribute__((ext_vector_type(8))) short short8;
typedef __attribute__((ext_vector_type(4))) float f32x4;

__constant__ int c_parents[J_] = {0,0,1,2,3,4,5,6,7,8,9,6,11,12,13,6,15,16,17,18,
                                  16,20,21,22,23,16,25,26,27,28,29,30,16,1,1};

static __device__ __forceinline__ unsigned short f2bf(float x) {
  union { float f; unsigned int u; } v; v.f = x;
  unsigned int r = v.u + 0x7FFF + ((v.u >> 16) & 1);   // round-to-nearest-even
  return (unsigned short)(r >> 16);
}

// ===== prep A (pure layout, fine-grained): ==================================
#define PA_WTS 245
#define PA_PD  2024                     // 184 e-chunks x 11 oct4-groups
#define PA_JB  644                      // 112*1472 octets / 256
#define PA_VS  365                      // ceil(32*V3/1024)
#define PA_BLOCKS (PA_WTS + PA_PD + PA_JB + PA_VS)
__global__ __launch_bounds__(256) void k_prep_a(
    const float* __restrict__ Jr,  const float* __restrict__ wts,
    const float* __restrict__ pd,  const float* __restrict__ sd,
    const float* __restrict__ vt,
    unsigned short* __restrict__ wtsB, unsigned short* __restrict__ pdT,
    unsigned short* __restrict__ JrBigT, float* __restrict__ vtsd) {
  int b = blockIdx.x;
  int t = threadIdx.x;
  if (b < PA_WTS) {                      // ---- wtsB bf16 ----
    int v   = b * 16 + (t >> 4);
    int jk0 = (t & 15) * 4;
    unsigned short pk[4];
#pragma unroll
    for (int i = 0; i < 4; ++i) {
      int j = jk0 + i;
      float x = (v < V_ && j < J_) ? wts[(size_t)v * J_ + j] : 0.f;
      pk[i] = f2bf(x);
    }
    *(unsigned long long*)(wtsB + (size_t)v * 64 + jk0) = *(unsigned long long*)pk;
  } else if (b < PA_WTS + PA_PD) {       // ---- pdT2 bf16, fragment order ----
    int pp = b - PA_WTS;
    int ec = pp % 184, o4 = pp / 184;
    int e  = ec * 64 + (t & 63);
    int oc = o4 * 4 + (t >> 6);          // 0..43
    int k0 = oc * 8;
    bool ev = e < V3;
    union { unsigned short u[8]; short8 s; } pk;
#pragma unroll
    for (int ii = 0; ii < 8; ++ii) {
      int k = k0 + ii;
      float x = 0.f;
      if (ev && k < PF_K)            x = pd[(size_t)k * V3 + e];
      else if (ev && k < PF_K + NB_) x = sd[(size_t)(k - PF_K) * V3 + e];
      pk.u[ii] = f2bf(x);
    }
    size_t dst = (size_t)(e >> 4) * 704 + (size_t)(oc >> 2) * 64
               + (oc & 3) * 16 + (e & 15);
    *(short8*)(pdT + dst * 8) = pk.s;
  } else if (b < PA_WTS + PA_PD + PA_JB) {  // ---- JrBig2 bf16, fragment order ----
    int o = (b - (PA_WTS + PA_PD)) * 256 + t;   // octet id, < 112*1472
    int jc = o / 1472;
    int oc = o - jc * 1472;              // e-octet within row
    int eo = oc * 8;
    int jj = jc / 3, cc = jc - jj * 3;
    union { unsigned short u[8]; short8 s; } pk;
#pragma unroll
    for (int i = 0; i < 8; ++i) {
      int e = eo + i;
      int v = e / 3, ce = e - v * 3;
      float x = (jc < 105 && e < V3 && ce == cc) ? Jr[v * J_ + jj] : 0.f;
      pk.u[i] = f2bf(x);
    }
    size_t dst = (size_t)(oc >> 2) * 448 + (size_t)(jc >> 4) * 64
               + (oc & 3) * 16 + (jc & 15);
    *(short8*)(JrBigT + dst * 8) = pk.s;
  } else {                               // ---- vtsd copy ----
    int f0 = (b - (PA_WTS + PA_PD + PA_JB)) * 1024 + t * 4;
#pragma unroll
    for (int k = 0; k < 4; ++k) {
      int f = f0 + k;
      if (f < 32 * V3) {
        int row = f / V3, col = f - row * V3;
        float x = 0.f;
        if (row == 0) x = vt[col];
        else if (row <= NB_) x = sd[(size_t)(row - 1) * V3 + col];
        vtsd[f] = x;
      }
    }
  }
}

// ===== jrgemm: planes[kb][row][jc] = sum_{e in chunk} JrBig[jc][e]*X[row][e]
// rows 0..511 from X (bodies); rows 512..543 from X2 (vtsd). MFMA bf16.
__global__ __launch_bounds__(64) void k_jrgemm(
    const float* __restrict__ X, const float* __restrict__ X2,
    const unsigned short* __restrict__ JrBigT, float* __restrict__ planes) {
  int lane = threadIdx.x;
  int q = lane >> 4, c = lane & 15;
  int row = blockIdx.x * 16 + c;
  int kb = blockIdx.y;
  int e0 = kb * ECH;
  const float* xr = (row < N_) ? X + (size_t)row * V3
                               : X2 + (size_t)(row - N_) * V3;
  const short8* Ap = (const short8*)JrBigT;

  f32x4 acc[7];
#pragma unroll
  for (int tt = 0; tt < 7; ++tt) acc[tt] = (f32x4){0.f, 0.f, 0.f, 0.f};

  bool safe = (e0 + ECH <= V3);
  if (safe) {
#pragma unroll
    for (int ks = 0; ks < ECH / 32; ++ks) {
      int eb = e0 + ks * 32 + q * 8;
      f32x4 x0 = *(const f32x4*)(xr + eb);
      f32x4 x1 = *(const f32x4*)(xr + eb + 4);
      union { unsigned short u[8]; short8 s; } bq;
#pragma unroll
      for (int i = 0; i < 4; ++i) { bq.u[i] = f2bf(x0[i]); bq.u[4 + i] = f2bf(x1[i]); }
#pragma unroll
      for (int tt = 0; tt < 7; ++tt) {
        short8 a = Ap[(size_t)(kb * 16 + ks) * 448 + tt * 64 + lane];
        acc[tt] = __builtin_amdgcn_mfma_f32_16x16x32_bf16(a, bq.s, acc[tt], 0, 0, 0);
      }
    }
  } else {                               // last chunk: zero-guard e >= V3
#pragma unroll
    for (int ks = 0; ks < ECH / 32; ++ks) {
      int eb = e0 + ks * 32 + q * 8;
      union { unsigned short u[8]; short8 s; } bq;
#pragma unroll
      for (int i = 0; i < 8; ++i) {
        int e = eb + i;
        float x = (e < V3) ? xr[e] : 0.f;
        bq.u[i] = f2bf(x);
      }
#pragma unroll
      for (int tt = 0; tt < 7; ++tt) {
        short8 a = Ap[(size_t)(kb * 16 + ks) * 448 + tt * 64 + lane];
        acc[tt] = __builtin_amdgcn_mfma_f32_16x16x32_bf16(a, bq.s, acc[tt], 0, 0, 0);
      }
    }
  }

  float* pl = planes + (size_t)kb * PLN + (size_t)row * JCP;
#pragma unroll
  for (int tt = 0; tt < 7; ++tt)
    *(f32x4*)(pl + tt * 16 + q * 4) = acc[tt];
}

// ===== fold: rows [row0, row0+total/105) -> dst (n<512) / dst2 (n>=512) =====
__global__ __launch_bounds__(256) void k_fold(
    const float* __restrict__ planes, float* __restrict__ dst,
    float* __restrict__ dst2, int row0, int total) {
  int g = blockIdx.x * 256 + threadIdx.x;
  if (g >= total) return;
  int n = row0 + g / 105, jc = g % 105;
  float s = 0.f;
#pragma unroll
  for (int kb = 0; kb < KB_; ++kb)
    s += planes[(size_t)kb * PLN + n * JCP + jc];
  if (n < N_) dst[n * 105 + jc] = s;
  else dst2[(n - N_) * 105 + jc] = s;
}

// ===== Rodrigues + inline Jp plane-fold + chain -> Rs, pfA, AwB =============
// One wave per body, wave-private LDS, no barriers.
__global__ __launch_bounds__(64) void k_chain_rod(
    const float* __restrict__ theta, const float* __restrict__ planes,
    const float* __restrict__ vtsdJr,
    const float* __restrict__ se,    const float* __restrict__ trans,
    const float* __restrict__ beta,
    float* __restrict__ Rs_out, unsigned short* __restrict__ pfA,
    unsigned short* __restrict__ AwB) {
  __shared__ float loc[J_][12];
  __shared__ float res[J_][12];
  __shared__ float Jp_s[J_][3];
  int l = threadIdx.x;
  int n = blockIdx.x;
  int mt = n >> 4, m = n & 15;

  float r[9];
  if (l < J_) {
    int j = l;
    const float* th = theta + n * (J_ * 3) + j * 3;
    float t0 = th[0], t1 = th[1], t2 = th[2];
    float angle = sqrtf(t0 * t0 + t1 * t1 + t2 * t2 + 1e-8f);
    float inv = 1.0f / angle;
    float r0 = t0 * inv, r1 = t1 * inv, r2 = t2 * inv;
    float s, c;
    sincosf(angle, &s, &c);
    float omc = 1.0f - c;
    r[0] = c + omc * r0 * r0;      r[1] = omc * r0 * r1 - s * r2;  r[2] = omc * r0 * r2 + s * r1;
    r[3] = omc * r1 * r0 + s * r2; r[4] = c + omc * r1 * r1;       r[5] = omc * r1 * r2 - s * r0;
    r[6] = omc * r2 * r0 - s * r1; r[7] = omc * r2 * r1 + s * r0;  r[8] = c + omc * r2 * r2;

    float* ro = Rs_out + (size_t)n * (J_ * 9) + j * 9;
#pragma unroll
    for (int k = 0; k < 9; ++k) ro[k] = r[k];
    if (j > 0) {
#pragma unroll
      for (int kk = 0; kk < 9; ++kk) {
        int k = (j - 1) * 9 + kk;
        float v = r[kk] - ((kk == 0 || kk == 4 || kk == 8) ? 1.0f : 0.0f);
        size_t idx = ((((size_t)mt * KS2 + (k >> 5)) * 4 + ((k >> 3) & 3)) * 16 + m) * 8 + (k & 7);
        pfA[idx] = f2bf(v);
      }
    }
    // Jp finalize: Jp = sum_kb planes[kb][n] + vtJr + beta @ sdJr
    const float* bn = beta + n * NB_;
#pragma unroll
    for (int cc = 0; cc < 3; ++cc) {
      int jc = j * 3 + cc;
      float val = vtsdJr[jc];
#pragma unroll
      for (int kb = 0; kb < KB_; ++kb)
        val += planes[(size_t)kb * PLN + n * JCP + jc];
#pragma unroll
      for (int bb = 0; bb < NB_; ++bb)
        val += bn[bb] * vtsdJr[(1 + bb) * 105 + jc];
      Jp_s[j][cc] = val;
    }
  } else {
    // lanes 35..63: AwB j-pad zero + pfA beta rows + pfA k-pad zeros
    unsigned short* An = AwB + (size_t)n * 16 * 64 + l;
#pragma unroll
    for (int d = 0; d < 16; ++d) An[d * 64] = 0;
    if (l < 55) {                    // beta -> k = 306 + (l-35)
      int k = PF_K + (l - 35);
      size_t idx = ((((size_t)mt * KS2 + (k >> 5)) * 4 + ((k >> 3) & 3)) * 16 + m) * 8 + (k & 7);
      pfA[idx] = f2bf(beta[n * NB_ + (l - 35)]);
    } else {                         // zeros k = 326..351
      for (int k = PF_K + NB_ + (l - 55); k < KP2; k += 9) {
        size_t idx = ((((size_t)mt * KS2 + (k >> 5)) * 4 + ((k >> 3) & 3)) * 16 + m) * 8 + (k & 7);
        pfA[idx] = 0;
      }
    }
  }
  // no barrier: single wave, LDS deps are in-order within a wave

  if (l < J_) {
    int j = l;
    if (j == 0) {
#pragma unroll
      for (int rr = 0; rr < 3; ++rr) {
        loc[0][rr * 4 + 0] = r[rr * 3 + 0];
        loc[0][rr * 4 + 1] = r[rr * 3 + 1];
        loc[0][rr * 4 + 2] = r[rr * 3 + 2];
        loc[0][rr * 4 + 3] = Jp_s[0][rr];
      }
#pragma unroll
      for (int k = 0; k < 12; ++k) res[0][k] = loc[0][k];
    } else {
      int p = c_parents[j];
      float si[3], sp[3], jh[3];
#pragma unroll
      for (int cidx = 0; cidx < 3; ++cidx) {
        si[cidx] = se[n * 105 + j * 3 + cidx];
        sp[cidx] = se[n * 105 + p * 3 + cidx];
        jh[cidx] = Jp_s[j][cidx] - Jp_s[p][cidx];
      }
#pragma unroll
      for (int rr = 0; rr < 3; ++rr) {
        float invp = 1.0f / sp[rr];
        loc[j][rr * 4 + 0] = r[rr * 3 + 0] * si[0] * invp;
        loc[j][rr * 4 + 1] = r[rr * 3 + 1] * si[1] * invp;
        loc[j][rr * 4 + 2] = r[rr * 3 + 2] * si[2] * invp;
        loc[j][rr * 4 + 3] = jh[rr];
      }
    }
  }

  for (int i = 1; i < J_; ++i) {
    if (l < 12) {
      int p = c_parents[i];
      int rr = l >> 2, cc = l & 3;
      float acc = (cc == 3) ? res[p][rr * 4 + 3] : 0.f;
#pragma unroll
      for (int k = 0; k < 3; ++k)
        acc += res[p][rr * 4 + k] * loc[i][k * 4 + cc];
      res[i][l] = acc;
    }
  }

  if (l < J_) {
    int j = l;
    float jx = Jp_s[j][0];
    float jy = Jp_s[j][1];
    float jz = Jp_s[j][2];
    unsigned short* An = AwB + (size_t)n * 16 * 64 + j;
#pragma unroll
    for (int rr = 0; rr < 3; ++rr) {
      float a0 = res[j][rr * 4 + 0];
      float a1 = res[j][rr * 4 + 1];
      float a2 = res[j][rr * 4 + 2];
      float a3 = res[j][rr * 4 + 3] - (a0 * jx + a1 * jy + a2 * jz)
               + trans[n * 3 + rr];
      An[(rr * 4 + 0) * 64] = f2bf(a0);
      An[(rr * 4 + 1) * 64] = f2bf(a1);
      An[(rr * 4 + 2) * 64] = f2bf(a2);
      An[(rr * 4 + 3) * 64] = f2bf(a3);
    }
  }
}

// ===== fused: v_posed (MFMA K=352) + LDS + skin (MFMA) -> verts =============
// grid(49, 8) x 512 threads (8 waves): wave owns a 32-e strip in phase 1
// (acc[4][2]) and 8 n-rows in phases 2b/3. Same LDS (62.5KB), 2x waves ->
// occupancy 13% -> ~38%, hiding HBM latency.
#define LSTR 244
__global__ __launch_bounds__(512) void k_vposed_skin(
    const unsigned short* __restrict__ pfA, const unsigned short* __restrict__ pdT,
    const unsigned short* __restrict__ AwB, const unsigned short* __restrict__ wtsB,
    const float* __restrict__ vt, const float* __restrict__ deform,
    float* __restrict__ verts) {
  __shared__ float lds[64 * LSTR];
  int t = threadIdx.x;
  int wv = t >> 6, lane = t & 63;       // wv 0..7
  int q = lane >> 4, col = lane & 15;
  int bx = blockIdx.x, by = blockIdx.y;
  int mtg0 = by * 4;
  int e16b = bx * 15 + wv * 2;          // wave's 32-e strip base (16-e units)

  const short8* Ap = (const short8*)pfA;
  const short8* Bp = (const short8*)pdT;

  // ---- phase 1: [pf|beta] @ [pd;sd]  (K=352, M=64, 32 e per wave) ----
  f32x4 acc[4][2];
#pragma unroll
  for (int mt = 0; mt < 4; ++mt)
#pragma unroll
    for (int et = 0; et < 2; ++et) acc[mt][et] = (f32x4){0.f, 0.f, 0.f, 0.f};

#pragma unroll
  for (int ks = 0; ks < KS2; ++ks) {
    short8 a[4];
#pragma unroll
    for (int mt = 0; mt < 4; ++mt)
      a[mt] = Ap[(((mtg0 + mt) * KS2 + ks) * 4 + q) * 16 + col];
    short8 b[2];
#pragma unroll
    for (int et = 0; et < 2; ++et)
      b[et] = Bp[(size_t)(e16b + et) * 704 + ks * 64 + lane];
#pragma unroll
    for (int mt = 0; mt < 4; ++mt)
#pragma unroll
      for (int et = 0; et < 2; ++et)
        acc[mt][et] = __builtin_amdgcn_mfma_f32_16x16x32_bf16(a[mt], b[et], acc[mt][et], 0, 0, 0);
  }

  // ---- phase 2a: stage raw acc into LDS ----
#pragma unroll
  for (int et = 0; et < 2; ++et) {
    int e_loc = wv * 32 + et * 16 + col;
    if (e_loc < 240) {
#pragma unroll
      for (int mt = 0; mt < 4; ++mt)
#pragma unroll
        for (int r = 0; r < 4; ++r)
          lds[(mt * 16 + q * 4 + r) * LSTR + e_loc] = acc[mt][et][r];
    }
  }
  __syncthreads();

  // ---- phase 2b: += vt + deform (vec4, wave-local rows; no barrier after) --
  if (lane < 60) {
    int e = bx * 240 + lane * 4;
    bool full = (e + 4 <= V3);
    f32x4 vt4 = (f32x4){0.f, 0.f, 0.f, 0.f};
    if (full) vt4 = *(const f32x4*)(vt + e);
    else {
#pragma unroll
      for (int k2 = 0; k2 < 4; ++k2) if (e + k2 < V3) vt4[k2] = vt[e + k2];
    }
#pragma unroll
    for (int i = 0; i < 8; ++i) {
      int n_loc = wv * 8 + i;
      int n = by * 64 + n_loc;
      const float* dp = deform + (size_t)n * V3 + e;
      f32x4 d4 = (f32x4){0.f, 0.f, 0.f, 0.f};
      if (full) d4 = *(const f32x4*)dp;
      else {
#pragma unroll
        for (int k2 = 0; k2 < 4; ++k2) if (e + k2 < V3) d4[k2] = dp[k2];
      }
      f32x4* lp = (f32x4*)&lds[n_loc * LSTR + lane * 4];
      *lp = *lp + vt4 + d4;
    }
  }

  // ---- phase 3: skin via MFMA, write final verts (rows wave-local) ----
  short8 bw0[5], bw1[5];
#pragma unroll
  for (int v5 = 0; v5 < 5; ++v5) {
    int v = bx * 80 + v5 * 16 + col;
    const short8* Wp = (const short8*)(wtsB + (size_t)v * 64);
    bw0[v5] = Wp[q];
    bw1[v5] = Wp[4 + q];
  }
#pragma unroll 2
  for (int ni = 0; ni < 8; ++ni) {
    int n_loc = wv * 8 + ni;
    int n = by * 64 + n_loc;
    const short8* Aq = (const short8*)(AwB + ((size_t)n * 16 + col) * 64);
    short8 a0 = Aq[q];
    short8 a1 = Aq[4 + q];
#pragma unroll
    for (int v5 = 0; v5 < 5; ++v5) {
      f32x4 s = (f32x4){0.f, 0.f, 0.f, 0.f};
      s = __builtin_amdgcn_mfma_f32_16x16x32_bf16(a0, bw0[v5], s, 0, 0, 0);
      s = __builtin_amdgcn_mfma_f32_16x16x32_bf16(a1, bw1[v5], s, 0, 0, 0);
      int vl = v5 * 16 + col;
      int v = bx * 80 + vl;
      if (v < V_ && q < 3) {
        float x = lds[n_loc * LSTR + 3 * vl + 0];
        float y = lds[n_loc * LSTR + 3 * vl + 1];
        float z = lds[n_loc * LSTR + 3 * vl + 2];
        verts[(size_t)n * V3 + 3 * v + q] = s[0] * x + s[1] * y + s[2] * z + s[3];
      }
    }
  }
}

extern "C" void kernel_launch(void* const* d_in, const int* in_sizes, int n_in,
                              void* d_out, int out_size, void* d_ws, size_t ws_size,
                              hipStream_t stream) {
  const float* beta   = (const float*)d_in[0];
  const float* theta  = (const float*)d_in[1];
  const float* se     = (const float*)d_in[2];
  const float* deform = (const float*)d_in[3];
  const float* trans  = (const float*)d_in[4];
  const float* vt     = (const float*)d_in[5];
  const float* sd     = (const float*)d_in[6];
  const float* pd     = (const float*)d_in[7];
  const float* Jr     = (const float*)d_in[8];
  const float* wts    = (const float*)d_in[9];

  float* out    = (float*)d_out;
  float* verts  = out;
  float* joints = out + (size_t)N_ * V3;
  float* Rs     = joints + (size_t)N_ * 105;

  char* w = (char*)d_ws;
  unsigned short* pdT    = (unsigned short*)w;                   //  8,290,304 B
  unsigned short* pfA    = (unsigned short*)(w + 8290304);       //    360,448 B
  float* planes = (float*)(w + 8650752);                         //  5,605,376 B (23 planes x 544 rows)
  float* JpRawF = (float*)(w + 14256128);                        //    215,040 B (unused dst slot)
  unsigned short* AwB    = (unsigned short*)(w + 14471168);      //  1,048,576 B
  unsigned short* wtsB   = (unsigned short*)(w + 15519744);      //    501,760 B
  unsigned short* JrBigT = (unsigned short*)(w + 16021504);      //  2,637,824 B
  float* vtsd   = (float*)(w + 18659328);                        //  1,493,376 B (32 x V3)
  float* vtsdJr = (float*)(w + 20152704);                        //      8,820 B

  k_prep_a<<<PA_BLOCKS, 256, 0, stream>>>(Jr, wts, pd, sd, vt,
                                          wtsB, pdT, JrBigT, vtsd);
  k_jrgemm<<<dim3(34, KB_), 64, 0, stream>>>(deform, vtsd, JrBigT, planes);
  k_fold<<<9, 256, 0, stream>>>(planes, JpRawF, vtsdJr, N_, 21 * 105);
  k_chain_rod<<<N_, 64, 0, stream>>>(theta, planes, vtsdJr, se, trans, beta,
                                     Rs, pfA, AwB);
  k_vposed_skin<<<dim3(49, 8), 512, 0, stream>>>(pfA, pdT, AwB, wtsB, vt, deform, verts);
  k_jrgemm<<<dim3(32, KB_), 64, 0, stream>>>(verts, verts, JrBigT, planes);
  k_fold<<<210, 256, 0, stream>>>(planes, joints, vtsdJr, 0, N_ * 105);
}